// Round 1
// baseline (153.911 us; speedup 1.0000x reference)
//
#include <hip/hip_runtime.h>

#define T_DIM 8192
#define H_DIM 4096
#define TPD 4
#define EPS 1e-6f

// One block per row. 256 threads; each thread handles 4 float4 chunks
// (16 floats) of the 4096-wide row. x kept in registers between the
// sum/variance pass and the normalize/write pass -> single HBM pass.
__global__ __launch_bounds__(256) void fused_ar_add_rmsnorm(
    const float* __restrict__ hs,   // [TPD, T, H]
    const float* __restrict__ res,  // [T, H]
    const float* __restrict__ w,    // [H]
    float* __restrict__ out)        // [T, H]
{
    const int row = blockIdx.x;
    const int tid = threadIdx.x;
    const size_t rowoff = (size_t)row * H_DIM;
    const size_t plane  = (size_t)T_DIM * H_DIM;

    float4 x[4];
    float ssq = 0.f;

    #pragma unroll
    for (int i = 0; i < 4; ++i) {
        const size_t col = (size_t)(tid + i * 256) * 4;   // float index within row
        const float4 h0 = *(const float4*)(hs + 0 * plane + rowoff + col);
        const float4 h1 = *(const float4*)(hs + 1 * plane + rowoff + col);
        const float4 h2 = *(const float4*)(hs + 2 * plane + rowoff + col);
        const float4 h3 = *(const float4*)(hs + 3 * plane + rowoff + col);
        const float4 r  = *(const float4*)(res + rowoff + col);
        float4 v;
        v.x = h0.x + h1.x + h2.x + h3.x + r.x;
        v.y = h0.y + h1.y + h2.y + h3.y + r.y;
        v.z = h0.z + h1.z + h2.z + h3.z + r.z;
        v.w = h0.w + h1.w + h2.w + h3.w + r.w;
        x[i] = v;
        ssq += v.x * v.x + v.y * v.y + v.z * v.z + v.w * v.w;
    }

    // wave (64-lane) shuffle reduction
    #pragma unroll
    for (int off = 32; off > 0; off >>= 1)
        ssq += __shfl_down(ssq, off, 64);

    __shared__ float wsum[4];
    const int lane = tid & 63;
    const int wid  = tid >> 6;
    if (lane == 0) wsum[wid] = ssq;
    __syncthreads();
    const float total = wsum[0] + wsum[1] + wsum[2] + wsum[3];  // LDS broadcast
    const float scale = rsqrtf(total * (1.0f / (float)H_DIM) + EPS);

    #pragma unroll
    for (int i = 0; i < 4; ++i) {
        const size_t col = (size_t)(tid + i * 256) * 4;
        const float4 wv = *(const float4*)(w + col);
        const float4 v = x[i];
        float4 o;
        o.x = v.x * scale * wv.x;
        o.y = v.y * scale * wv.y;
        o.z = v.z * scale * wv.z;
        o.w = v.w * scale * wv.w;
        *(float4*)(out + rowoff + col) = o;
    }
}

extern "C" void kernel_launch(void* const* d_in, const int* in_sizes, int n_in,
                              void* d_out, int out_size, void* d_ws, size_t ws_size,
                              hipStream_t stream) {
    const float* hs  = (const float*)d_in[0];  // [4, 8192, 4096]
    const float* res = (const float*)d_in[1];  // [8192, 4096]
    const float* w   = (const float*)d_in[2];  // [4096]
    float* out = (float*)d_out;                // [8192, 4096]

    fused_ar_add_rmsnorm<<<T_DIM, 256, 0, stream>>>(hs, res, w, out);
}

// Round 3
// 129.600 us; speedup vs baseline: 1.1876x; 1.1876x over previous
//
#include <hip/hip_runtime.h>

#define T_DIM 8192
#define H_DIM 4096
#define EPS 1e-6f

typedef float fx4 __attribute__((ext_vector_type(4)));

// One block per row, 256 threads, 16 floats/thread held in registers
// between the sum/variance pass and the normalize/write pass.
// All big streams (4 hs planes, residual, out) are touched exactly once
// and exceed L3 (800 MB > 256 MB) -> non-temporal hints on every
// streaming access; only weight (16 KB, reused by all blocks) is cached.
// fx4 (clang ext_vector_type) instead of HIP float4: the nontemporal
// builtins only accept scalar/vector types, not the HIP_vector_type class.
__global__ __launch_bounds__(256) void fused_ar_add_rmsnorm(
    const float* __restrict__ hs,   // [4, T, H]
    const float* __restrict__ res,  // [T, H]
    const float* __restrict__ w,    // [H]
    float* __restrict__ out)        // [T, H]
{
    const int row = blockIdx.x;
    const int tid = threadIdx.x;
    const size_t rowoff = (size_t)row * H_DIM;
    const size_t plane  = (size_t)T_DIM * H_DIM;

    const fx4* p0 = (const fx4*)(hs + rowoff);
    const fx4* p1 = (const fx4*)(hs + plane + rowoff);
    const fx4* p2 = (const fx4*)(hs + 2 * plane + rowoff);
    const fx4* p3 = (const fx4*)(hs + 3 * plane + rowoff);
    const fx4* pr = (const fx4*)(res + rowoff);

    fx4 x[4];
    float ssq = 0.f;

    #pragma unroll
    for (int i = 0; i < 4; ++i) {
        const int c = tid + i * 256;            // float4 index within row
        const fx4 h0 = __builtin_nontemporal_load(p0 + c);
        const fx4 h1 = __builtin_nontemporal_load(p1 + c);
        const fx4 h2 = __builtin_nontemporal_load(p2 + c);
        const fx4 h3 = __builtin_nontemporal_load(p3 + c);
        const fx4 r  = __builtin_nontemporal_load(pr + c);
        const fx4 v = h0 + h1 + h2 + h3 + r;
        x[i] = v;
        ssq += v.x * v.x + v.y * v.y + v.z * v.z + v.w * v.w;
    }

    // 64-lane wave shuffle reduction
    #pragma unroll
    for (int off = 32; off > 0; off >>= 1)
        ssq += __shfl_down(ssq, off, 64);

    __shared__ float wsum[4];
    const int lane = tid & 63;
    const int wid  = tid >> 6;
    if (lane == 0) wsum[wid] = ssq;
    __syncthreads();
    const float total = wsum[0] + wsum[1] + wsum[2] + wsum[3];
    const float scale = rsqrtf(total * (1.0f / (float)H_DIM) + EPS);

    const fx4* pw = (const fx4*)w;
    fx4* po = (fx4*)(out + rowoff);

    #pragma unroll
    for (int i = 0; i < 4; ++i) {
        const int c = tid + i * 256;
        const fx4 wv = pw[c];                   // cached: reused by all blocks
        const fx4 o = x[i] * scale * wv;
        __builtin_nontemporal_store(o, po + c);
    }
}

extern "C" void kernel_launch(void* const* d_in, const int* in_sizes, int n_in,
                              void* d_out, int out_size, void* d_ws, size_t ws_size,
                              hipStream_t stream) {
    const float* hs  = (const float*)d_in[0];  // [4, 8192, 4096]
    const float* res = (const float*)d_in[1];  // [8192, 4096]
    const float* w   = (const float*)d_in[2];  // [4096]
    float* out = (float*)d_out;                // [8192, 4096]

    fused_ar_add_rmsnorm<<<T_DIM, 256, 0, stream>>>(hs, res, w, out);
}